// Round 3
// baseline (99.238 us; speedup 1.0000x reference)
//
#include <hip/hip_runtime.h>
#include <cstdint>

// Problem constants (match reference)
#define BB 32
#define NN 32768
#define CC 21
#define K1_BLK 256
#define K1_GRID ((BB * NN) / K1_BLK)          // 4096
#define CONF_FLOATS (K1_BLK * CC)             // 5376 floats staged per block
#define CONF_VEC4 (CONF_FLOATS / 4)           // 1344 float4 (= 21 full waves)

// K2 geometry
#define K2T 1024
#define NWAVE (K2T / 64)
#define KPT (NN / K2T)                         // 32 keys per thread

// ---------------------------------------------------------------------------
// K1: per-prior lse, mining key, positive CE, SmoothL1; block partials.
// v3: async global->LDS staging (no VGPR round-trip), early label/pred/gt
// prefetch so each block pays ~one overlapped HBM round-trip.
// ---------------------------------------------------------------------------
__global__ __launch_bounds__(K1_BLK) void k1_compute(
    const float* __restrict__ conf, const float* __restrict__ pred,
    const int* __restrict__ labels, const float* __restrict__ gt,
    unsigned* __restrict__ keys, float* __restrict__ pce,
    float* __restrict__ psl1, int* __restrict__ row_npos)
{
    __shared__ __align__(16) float lconf[CONF_FLOATS];
    __shared__ float wce[4], wsl[4];
    __shared__ int   wcnt[4];

    const int tid = threadIdx.x;
    const int lane = tid & 63;
    const int wid = tid >> 6;
    const size_t p0 = (size_t)blockIdx.x * K1_BLK;
    const size_t p = p0 + tid;

    // issue label load FIRST (its waitcnt then won't drain the staging queue)
    const int lab = labels[p];

    // async direct global->LDS staging, 16B/lane, all in flight at once.
    // 1344 vec4 = 21 full waves -> the i==5 guard is wave-uniform.
    const float4* c4 = reinterpret_cast<const float4*>(conf + p0 * CC);
#pragma unroll
    for (int i = 0; i < 6; ++i) {
        const int v = tid + i * K1_BLK;
        if (v < CONF_VEC4) {
            __builtin_amdgcn_global_load_lds(
                (const __attribute__((address_space(1))) unsigned*)(c4 + v),
                (__attribute__((address_space(3))) unsigned*)(&lconf[4 * v]),
                16, 0, 0);
        }
    }

    const bool pos = lab > 0;

    // sparse (~3%) SmoothL1: load + compute BEFORE the barrier so the
    // scattered loads overlap the staging drain.
    float sl = 0.f;
    if (pos) {
        const float* pp = pred + p * 5;
        const float* gg = gt + p * 5;
        float pv[5], gv[5];
#pragma unroll
        for (int j = 0; j < 5; ++j) { pv[j] = pp[j]; gv[j] = gg[j]; }
#pragma unroll
        for (int j = 0; j < 5; ++j) {
            float d = fabsf(pv[j] - gv[j]);
            sl += (d < 1.f) ? 0.5f * d * d : (d - 0.5f);
        }
    }

    __syncthreads();   // compiler emits vmcnt(0) drain -> LDS tile ready

    // lse without max subtraction: conf ~ N(0,1), exp fits f32 comfortably.
    const float* my = lconf + tid * CC;   // stride 21 (odd): 2-way aliasing, free
    float s = 0.f;
#pragma unroll
    for (int c = 0; c < CC; ++c) s += exp2f(my[c] * 1.44269504f);
    const float lse = 0.6931471805599453f * log2f(s);

    // mining = -logp0 = lse - conf0; clamp rounding-induced tiny negatives
    // (sign bit would break uint ordering).
    const float mining = fmaxf(lse - my[0], 0.f);
    keys[p] = pos ? 0u : __float_as_uint(mining);

    float ce = pos ? (lse - my[lab]) : 0.f;
    int cnt = pos ? 1 : 0;

    // wave shfl reduction (deterministic fixed tree)
#pragma unroll
    for (int d = 32; d > 0; d >>= 1) {
        ce  += __shfl_down(ce, d);
        sl  += __shfl_down(sl, d);
        cnt += __shfl_down(cnt, d);
    }
    if (lane == 0) { wce[wid] = ce; wsl[wid] = sl; wcnt[wid] = cnt; }
    __syncthreads();
    if (tid == 0) {
        float tce = 0.f, tsl = 0.f; int tc = 0;
#pragma unroll
        for (int w = 0; w < 4; ++w) { tce += wce[w]; tsl += wsl[w]; tc += wcnt[w]; }
        pce[blockIdx.x]  = tce;
        psl1[blockIdx.x] = tsl;
        atomicAdd(&row_npos[blockIdx.x >> 7], tc);  // 128 blocks per row
    }
}

// ---------------------------------------------------------------------------
// K2 v3: per-row top-k sum via register-resident integer bisection.
// Each thread holds 32 keys in VGPRs; <=31 rounds of count(key >= mid)
// with a block reduce converge to the exact kth-largest key T.
// sum of selected negatives' CE = sum(keys > T) + r*T (ties exact: a tied
// negative's CE equals T, so tie order is irrelevant).
// No LDS histograms, no atomics -> no same-address serialization.
// ---------------------------------------------------------------------------
__global__ __launch_bounds__(K2T) void k2_select(
    const unsigned* __restrict__ keys, const int* __restrict__ row_npos,
    double* __restrict__ row_sumneg)
{
    const int b = blockIdx.x;
    const int tid = threadIdx.x;
    const int lane = tid & 63;
    const int wid = tid >> 6;
    const unsigned* rk = keys + (size_t)b * NN;

    __shared__ unsigned swu[NWAVE];
    __shared__ double   swd[NWAVE];
    __shared__ unsigned s_u;

    // coalesced register-resident copy of this row's keys (static indexing)
    unsigned k_[KPT];
#pragma unroll
    for (int j = 0; j < KPT; ++j) k_[j] = rk[tid + j * K2T];

    const int k = 3 * row_npos[b];
    if (k <= 0) { if (tid == 0) row_sumneg[b] = 0.0; return; }  // uniform exit
    const unsigned want = (unsigned)((k > NN) ? NN : k);

    // block max -> tight bisection upper bound
    unsigned mx = 0;
#pragma unroll
    for (int j = 0; j < KPT; ++j) mx = (k_[j] > mx) ? k_[j] : mx;
#pragma unroll
    for (int d = 32; d > 0; d >>= 1) {
        unsigned o = __shfl_down(mx, d);
        mx = (o > mx) ? o : mx;
    }
    if (lane == 0) swu[wid] = mx;
    __syncthreads();
    if (tid == 0) {
        unsigned m2 = 0;
#pragma unroll
        for (int w = 0; w < NWAVE; ++w) m2 = (swu[w] > m2) ? swu[w] : m2;
        s_u = m2;
    }
    __syncthreads();
    unsigned lo = 0, hi = s_u;
    __syncthreads();  // s_u re-used below: ensure all read before overwrite

    // bisection: largest T with count(key >= T) >= want
    for (int it = 0; it < 31; ++it) {
        if (lo >= hi) break;   // uniform across block
        const unsigned mid =
            (unsigned)(((unsigned long long)lo + (unsigned long long)hi + 1ull) >> 1);
        int c = 0;
#pragma unroll
        for (int j = 0; j < KPT; ++j) c += (k_[j] >= mid) ? 1 : 0;
#pragma unroll
        for (int d = 32; d > 0; d >>= 1) c += __shfl_down(c, d);
        if (lane == 0) swu[wid] = (unsigned)c;
        __syncthreads();
        if (wid == 0) {
            unsigned cc = (lane < NWAVE) ? swu[lane] : 0;
#pragma unroll
            for (int d = 8; d > 0; d >>= 1) cc += __shfl_down(cc, d);
            if (lane == 0) s_u = cc;
        }
        __syncthreads();
        const unsigned cnt = s_u;
        if (cnt >= want) lo = mid; else hi = mid - 1;
    }
    const unsigned T = lo;

    // final: count and sum of keys strictly greater than T (registers only)
    int above = 0;
    double sel = 0.0;
#pragma unroll
    for (int j = 0; j < KPT; ++j) {
        const unsigned key = k_[j];
        if (key > T) { above++; sel += (double)__uint_as_float(key); }
    }
#pragma unroll
    for (int d = 32; d > 0; d >>= 1) {
        above += __shfl_down(above, d);
        sel   += __shfl_down(sel, d);
    }
    if (lane == 0) { swu[wid] = (unsigned)above; swd[wid] = sel; }
    __syncthreads();
    if (tid == 0) {
        unsigned atot = 0; double stot = 0.0;
#pragma unroll
        for (int w = 0; w < NWAVE; ++w) { atot += swu[w]; stot += swd[w]; }
        const int r = (int)want - (int)atot;   // # of ==T entries selected
        row_sumneg[b] = stot + (double)r * (double)__uint_as_float(T);
    }
}

// ---------------------------------------------------------------------------
// K3: deterministic final reduction -> two scalars.
// ---------------------------------------------------------------------------
__global__ __launch_bounds__(256) void k3_final(
    const float* __restrict__ pce, const float* __restrict__ psl1,
    const int* __restrict__ row_npos, const double* __restrict__ row_sumneg,
    float* __restrict__ out)
{
    __shared__ double a[256], c[256];
    const int tid = threadIdx.x;
    double ce = 0.0, sl = 0.0;
    for (int i = tid; i < K1_GRID; i += 256) {
        ce += (double)pce[i];
        sl += (double)psl1[i];
    }
    a[tid] = ce; c[tid] = sl;
    __syncthreads();
    for (int st = 128; st > 0; st >>= 1) {
        if (tid < st) { a[tid] += a[tid + st]; c[tid] += c[tid + st]; }
        __syncthreads();
    }
    if (tid == 0) {
        int np = 0; double ns = 0.0;
        for (int bb = 0; bb < BB; ++bb) { np += row_npos[bb]; ns += row_sumneg[bb]; }
        const double npos = (double)np;
        out[0] = (float)(c[0] / npos);          // smooth_l1_loss / n_pos
        out[1] = (float)((a[0] + ns) / npos);   // classification_loss / n_pos
    }
}

// ---------------------------------------------------------------------------
extern "C" void kernel_launch(void* const* d_in, const int* in_sizes, int n_in,
                              void* d_out, int out_size, void* d_ws, size_t ws_size,
                              hipStream_t stream)
{
    const float* conf   = (const float*)d_in[0];
    const float* pred   = (const float*)d_in[1];
    const int*   labels = (const int*)d_in[2];
    const float* gt     = (const float*)d_in[3];
    float* out = (float*)d_out;

    char* ws = (char*)d_ws;
    unsigned* keys      = (unsigned*)ws;                               // 4 MB
    float*    pce       = (float*)(ws + 4194304);                      // 16 KB
    float*    psl1      = (float*)(ws + 4194304 + 16384);              // 16 KB
    int*      row_npos  = (int*)(ws + 4194304 + 32768);                // 128 B
    double*   row_sumneg= (double*)(ws + 4194304 + 32768 + 128);       // 256 B

    hipMemsetAsync(row_npos, 0, BB * sizeof(int), stream);

    k1_compute<<<K1_GRID, K1_BLK, 0, stream>>>(conf, pred, labels, gt,
                                               keys, pce, psl1, row_npos);
    k2_select<<<BB, K2T, 0, stream>>>(keys, row_npos, row_sumneg);
    k3_final<<<1, 256, 0, stream>>>(pce, psl1, row_npos, row_sumneg, out);
}

// Round 4
// 82.707 us; speedup vs baseline: 1.1999x; 1.1999x over previous
//
#include <hip/hip_runtime.h>
#include <cstdint>

// Problem constants (match reference)
#define BB 32
#define NN 32768
#define CC 21
#define K1_BLK 256
#define K1_GRID ((BB * NN) / K1_BLK)          // 4096

// selection geometry
#define HBINS 2048                             // top-11-bit bins (sign=0)
#define K2T 1024
#define CAP 16384                              // 64 KB compact buffer

typedef float f4 __attribute__((ext_vector_type(4)));

// ---------------------------------------------------------------------------
// K1 v4: pure register streaming — no conf LDS tile, no staging barrier.
// Each thread: 7 independent loads, 21-exp lse walk, key + CE + SmoothL1.
// Also builds per-row 2048-bin histogram of key top bits (LDS 2-copy local,
// integer global-atomic flush -> deterministic).
// ---------------------------------------------------------------------------
__global__ __launch_bounds__(K1_BLK) void k1_compute(
    const float* __restrict__ conf, const float* __restrict__ pred,
    const int* __restrict__ labels, const float* __restrict__ gt,
    unsigned* __restrict__ keys, float* __restrict__ pce,
    float* __restrict__ psl1, int* __restrict__ row_npos,
    unsigned* __restrict__ ghist)
{
    __shared__ unsigned h2[HBINS * 2];        // 16 KB, 2 copies interleaved
    __shared__ float wce[4], wsl[4];
    __shared__ int   wcnt[4];

    const int tid = threadIdx.x;
    const int lane = tid & 63;
    const int wid = tid >> 6;
    const size_t p = (size_t)blockIdx.x * K1_BLK + tid;

    // zero local hist (barrier before use comes later)
#pragma unroll
    for (int i = 0; i < 16; ++i) h2[tid + i * K1_BLK] = 0;

    // all loads issued up-front, independent, no barrier needed
    const int lab = labels[p];
    const float* cp = conf + p * CC;
    f4 q0, q1, q2, q3, q4;
    __builtin_memcpy(&q0, cp +  0, 16);
    __builtin_memcpy(&q1, cp +  4, 16);
    __builtin_memcpy(&q2, cp +  8, 16);
    __builtin_memcpy(&q3, cp + 12, 16);
    __builtin_memcpy(&q4, cp + 16, 16);
    const float a20 = cp[20];
    const bool pos = lab > 0;

    // sparse (~3%) SmoothL1
    float sl = 0.f;
    if (pos) {
        const float* pp = pred + p * 5;
        const float* gg = gt + p * 5;
        float pv[5], gv[5];
#pragma unroll
        for (int j = 0; j < 5; ++j) { pv[j] = pp[j]; gv[j] = gg[j]; }
#pragma unroll
        for (int j = 0; j < 5; ++j) {
            float d = fabsf(pv[j] - gv[j]);
            sl += (d < 1.f) ? 0.5f * d * d : (d - 0.5f);
        }
    }

    // 21-class lse walk; logp[lab] gathered via unrolled selects
    float s = 0.f, clab = 0.f;
    const float a0 = q0.x;
#define KSTEP(VAL, IDX) { const float v_ = (VAL); \
        s += exp2f(v_ * 1.44269504f); \
        clab = (IDX == lab) ? v_ : clab; }
    KSTEP(q0.x, 0)  KSTEP(q0.y, 1)  KSTEP(q0.z, 2)  KSTEP(q0.w, 3)
    KSTEP(q1.x, 4)  KSTEP(q1.y, 5)  KSTEP(q1.z, 6)  KSTEP(q1.w, 7)
    KSTEP(q2.x, 8)  KSTEP(q2.y, 9)  KSTEP(q2.z, 10) KSTEP(q2.w, 11)
    KSTEP(q3.x, 12) KSTEP(q3.y, 13) KSTEP(q3.z, 14) KSTEP(q3.w, 15)
    KSTEP(q4.x, 16) KSTEP(q4.y, 17) KSTEP(q4.z, 18) KSTEP(q4.w, 19)
    KSTEP(a20, 20)
#undef KSTEP
    const float lse = 0.6931471805599453f * log2f(s);

    // mining = -logp0 = lse - conf0; clamp rounding-induced tiny negatives
    const float mining = fmaxf(lse - a0, 0.f);
    const unsigned key = pos ? 0u : __float_as_uint(mining);
    keys[p] = key;

    float ce = pos ? (lse - clab) : 0.f;
    int cnt = pos ? 1 : 0;

    // wave shfl reduction (deterministic fixed tree)
#pragma unroll
    for (int d = 32; d > 0; d >>= 1) {
        ce  += __shfl_down(ce, d);
        sl  += __shfl_down(sl, d);
        cnt += __shfl_down(cnt, d);
    }
    if (lane == 0) { wce[wid] = ce; wsl[wid] = sl; wcnt[wid] = cnt; }
    __syncthreads();   // covers hist zeroing AND wce/wsl/wcnt

    // local histogram of key top 11 bits (2 copies cut same-bin serialization)
    atomicAdd(&h2[((key >> 21) << 1) | (lane & 1)], 1u);

    if (tid == 0) {
        float tce = 0.f, tsl = 0.f; int tc = 0;
#pragma unroll
        for (int w = 0; w < 4; ++w) { tce += wce[w]; tsl += wsl[w]; tc += wcnt[w]; }
        pce[blockIdx.x]  = tce;
        psl1[blockIdx.x] = tsl;
        atomicAdd(&row_npos[blockIdx.x >> 7], tc);  // 128 blocks per row
    }
    __syncthreads();   // hist complete

    // flush nonzero bins to per-row global hist (integer atomics: deterministic)
    const int row = blockIdx.x >> 7;
#pragma unroll
    for (int i = 0; i < 8; ++i) {
        const int bn = tid + i * K1_BLK;
        const unsigned v = h2[bn << 1] + h2[(bn << 1) | 1];
        if (v) atomicAdd(&ghist[(size_t)row * HBINS + bn], v);
    }
}

// ---------------------------------------------------------------------------
// Parallel suffix-scan over 2048 bins + crossing pick (proven in v2).
// After return: *s_bin = largest bin with suffix >= want, *s_above = suffix
// count strictly above it.
// ---------------------------------------------------------------------------
template <class GET>
__device__ __forceinline__ void sscan(
    GET get, unsigned* ss, unsigned* swsum,
    int* s_bin, int* s_above, unsigned want, int tid, int lane, int wid)
{
    const int b0 = 2047 - 2 * tid;     // descending scan order
    const int b1 = 2046 - 2 * tid;
    const unsigned m0 = get(b0), m1 = get(b1);
    unsigned v = m0 + m1;
#pragma unroll
    for (int d = 1; d < 64; d <<= 1) {
        unsigned u = __shfl_up(v, d);
        if (lane >= d) v += u;
    }
    if (lane == 63) swsum[wid] = v;
    __syncthreads();
    if (wid == 0) {
        unsigned wv = (lane < 16) ? swsum[lane] : 0;
#pragma unroll
        for (int d = 1; d < 16; d <<= 1) {
            unsigned u = __shfl_up(wv, d);
            if (lane >= d) wv += u;
        }
        if (lane < 16) swsum[lane] = wv;
    }
    __syncthreads();
    const unsigned off = wid ? swsum[wid - 1] : 0;
    const unsigned incl = off + v;     // suffix through b1
    const unsigned sb0 = incl - m1;    // suffix through b0
    ss[b0] = sb0;
    ss[b1] = incl;
    __syncthreads();
    if (sb0 >= want && (b0 == 2047 || ss[b0 + 1] < want)) {
        *s_bin = b0; *s_above = (b0 == 2047) ? 0 : (int)ss[b0 + 1];
    }
    if (incl >= want && ss[b1 + 1] < want) {
        *s_bin = b1; *s_above = (int)ss[b1 + 1];
    }
    __syncthreads();
}

// ---------------------------------------------------------------------------
// K2 v4: per-row exact top-k sum. Level-1 hist precomputed by k1; one row
// pass (gather + sum-above); levels 2/3 refine on LDS-resident compact set.
// sum = Σ(key > T) + r·T  (ties exact: a tied negative's CE equals T).
// ---------------------------------------------------------------------------
__global__ __launch_bounds__(K2T) void k2_select(
    const unsigned* __restrict__ keys, const unsigned* __restrict__ ghist,
    const int* __restrict__ row_npos, double* __restrict__ row_sumneg)
{
    const int b = blockIdx.x;
    const int tid = threadIdx.x;
    const int lane = tid & 63;
    const int wid = tid >> 6;
    const unsigned* rk = keys + (size_t)b * NN;

    __shared__ unsigned gh[HBINS];            // 8 KB  level-1 counts
    __shared__ unsigned lh[HBINS * 2];        // 16 KB levels 2/3 (2 copies)
    __shared__ unsigned ss[HBINS];            // 8 KB  suffix sums
    __shared__ unsigned cbuf[CAP];            // 64 KB compacted keys
    __shared__ unsigned swsum[16];
    __shared__ double sdred[16];
    __shared__ int s_bin, s_above;
    __shared__ unsigned s_m;

    const int kk = 3 * row_npos[b];
    if (kk <= 0) { if (tid == 0) row_sumneg[b] = 0.0; return; }
    const unsigned want = (unsigned)((kk > NN) ? NN : kk);

    // ---- level 1: scan precomputed per-row hist
    gh[tid]        = ghist[(size_t)b * HBINS + tid];
    gh[tid + 1024] = ghist[(size_t)b * HBINS + tid + 1024];
    __syncthreads();
    sscan([&](int bn) { return gh[bn]; },
          ss, swsum, &s_bin, &s_above, want, tid, lane, wid);
    const int bsel1 = s_bin;
    unsigned want1 = want - (unsigned)s_above;
    const unsigned cnt1 = gh[bsel1];
    const bool fits = (cnt1 <= CAP);

    // ---- single row pass: sum-above (double, fixed tree) + gather matching
    if (tid == 0) s_m = 0;
    __syncthreads();
    double localAbove = 0.0;
    for (int i = tid; i < NN; i += K2T) {
        const unsigned key = rk[i];
        const int hb = (int)(key >> 21);
        if (hb > bsel1) localAbove += (double)__uint_as_float(key);
        const bool take = fits && (hb == bsel1);
        const unsigned long long mask = __ballot(take);
        if (mask) {
            const int leader = __ffsll((unsigned long long)mask) - 1;
            unsigned base = 0;
            if (lane == leader) base = atomicAdd(&s_m, (unsigned)__popcll(mask));
            base = __shfl(base, leader);
            if (take) {
                const unsigned pp = base +
                    (unsigned)__popcll(mask & ((1ull << lane) - 1ull));
                cbuf[pp] = key;   // pp < cnt1 <= CAP guaranteed
            }
        }
    }
    __syncthreads();
    const unsigned m = s_m;

    // ---- level 2: bits[20:10]
    for (int i = tid; i < HBINS * 2; i += K2T) lh[i] = 0;
    __syncthreads();
    if (fits) {
        for (unsigned j = tid; j < m; j += K2T) {
            const unsigned key = cbuf[j];
            atomicAdd(&lh[(((key >> 10) & 0x7FFu) << 1) | (lane & 1)], 1u);
        }
    } else {
        for (int i = tid; i < NN; i += K2T) {
            const unsigned key = rk[i];
            if ((int)(key >> 21) == bsel1)
                atomicAdd(&lh[(((key >> 10) & 0x7FFu) << 1) | (lane & 1)], 1u);
        }
    }
    __syncthreads();
    sscan([&](int bn) { return lh[bn << 1] + lh[(bn << 1) | 1]; },
          ss, swsum, &s_bin, &s_above, want1, tid, lane, wid);
    const unsigned bsel2 = (unsigned)s_bin;
    unsigned want2 = want1 - (unsigned)s_above;

    // ---- level 3: bits[9:0] (1024 bins; upper 1024 stay zero)
    for (int i = tid; i < HBINS * 2; i += K2T) lh[i] = 0;
    __syncthreads();
    if (fits) {
        for (unsigned j = tid; j < m; j += K2T) {
            const unsigned key = cbuf[j];
            if (((key >> 10) & 0x7FFu) == bsel2)
                atomicAdd(&lh[((key & 0x3FFu) << 1) | (lane & 1)], 1u);
        }
    } else {
        for (int i = tid; i < NN; i += K2T) {
            const unsigned key = rk[i];
            if ((int)(key >> 21) == bsel1 && ((key >> 10) & 0x7FFu) == bsel2)
                atomicAdd(&lh[((key & 0x3FFu) << 1) | (lane & 1)], 1u);
        }
    }
    __syncthreads();
    sscan([&](int bn) { return lh[bn << 1] + lh[(bn << 1) | 1]; },
          ss, swsum, &s_bin, &s_above, want2, tid, lane, wid);
    const int r = (int)want2 - s_above;           // # of ==T selected
    const unsigned T = ((unsigned)bsel1 << 21) | (bsel2 << 10) | (unsigned)s_bin;

    // ---- final: sum of in-bin keys strictly greater than T
    double localSel = 0.0;
    if (fits) {
        for (unsigned j = tid; j < m; j += K2T) {
            const unsigned key = cbuf[j];
            if (key > T) localSel += (double)__uint_as_float(key);
        }
    } else {
        for (int i = tid; i < NN; i += K2T) {
            const unsigned key = rk[i];
            if ((int)(key >> 21) == bsel1 && key > T)
                localSel += (double)__uint_as_float(key);
        }
    }
    double tot = localAbove + localSel;
#pragma unroll
    for (int d = 32; d > 0; d >>= 1) tot += __shfl_down(tot, d);
    if (lane == 0) sdred[wid] = tot;
    __syncthreads();
    if (tid == 0) {
        double sm = 0.0;
#pragma unroll
        for (int w = 0; w < 16; ++w) sm += sdred[w];
        row_sumneg[b] = sm + (double)r * (double)__uint_as_float(T);
    }
}

// ---------------------------------------------------------------------------
// K3: deterministic final reduction -> two scalars.
// ---------------------------------------------------------------------------
__global__ __launch_bounds__(256) void k3_final(
    const float* __restrict__ pce, const float* __restrict__ psl1,
    const int* __restrict__ row_npos, const double* __restrict__ row_sumneg,
    float* __restrict__ out)
{
    __shared__ double a[256], c[256];
    const int tid = threadIdx.x;
    double ce = 0.0, sl = 0.0;
    for (int i = tid; i < K1_GRID; i += 256) {
        ce += (double)pce[i];
        sl += (double)psl1[i];
    }
    a[tid] = ce; c[tid] = sl;
    __syncthreads();
    for (int st = 128; st > 0; st >>= 1) {
        if (tid < st) { a[tid] += a[tid + st]; c[tid] += c[tid + st]; }
        __syncthreads();
    }
    if (tid == 0) {
        int np = 0; double ns = 0.0;
        for (int bb = 0; bb < BB; ++bb) { np += row_npos[bb]; ns += row_sumneg[bb]; }
        const double npos = (double)np;
        out[0] = (float)(c[0] / npos);          // smooth_l1_loss / n_pos
        out[1] = (float)((a[0] + ns) / npos);   // classification_loss / n_pos
    }
}

// ---------------------------------------------------------------------------
extern "C" void kernel_launch(void* const* d_in, const int* in_sizes, int n_in,
                              void* d_out, int out_size, void* d_ws, size_t ws_size,
                              hipStream_t stream)
{
    const float* conf   = (const float*)d_in[0];
    const float* pred   = (const float*)d_in[1];
    const int*   labels = (const int*)d_in[2];
    const float* gt     = (const float*)d_in[3];
    float* out = (float*)d_out;

    char* ws = (char*)d_ws;
    unsigned* keys       = (unsigned*)ws;                      // 4 MB
    unsigned* ghist      = (unsigned*)(ws + 4194304);          // 256 KB
    int*      row_npos   = (int*)(ws + 4456448);               // 128 B
    double*   row_sumneg = (double*)(ws + 4456576);            // 256 B
    float*    pce        = (float*)(ws + 4456832);             // 16 KB
    float*    psl1       = (float*)(ws + 4473216);             // 16 KB

    // zero ghist + row_npos in one contiguous async memset
    hipMemsetAsync(ghist, 0, 262144 + 128, stream);

    k1_compute<<<K1_GRID, K1_BLK, 0, stream>>>(conf, pred, labels, gt,
                                               keys, pce, psl1, row_npos, ghist);
    k2_select<<<BB, K2T, 0, stream>>>(keys, ghist, row_npos, row_sumneg);
    k3_final<<<1, 256, 0, stream>>>(pce, psl1, row_npos, row_sumneg, out);
}

// Round 5
// 53.568 us; speedup vs baseline: 1.8526x; 1.5440x over previous
//
#include <hip/hip_runtime.h>
#include <cstdint>

// Problem constants (match reference)
#define BB 32
#define NN 32768
#define CC 21
#define K1_BLK 256
#define PPT 2                                  // priors per thread
#define TILE (K1_BLK * PPT)                    // 512
#define K1_GRID ((BB * NN) / TILE)             // 2048
#define BLKROW (NN / TILE)                     // 64 k1-blocks per row

// K2 geometry
#define K2T 1024
#define CAP 16384                              // 64 KB compact buffer

typedef float f4 __attribute__((ext_vector_type(4)));

// native transcendentals (1-ulp; output threshold is 0.39 absolute -> huge slack)
__device__ __forceinline__ float fexp2(float x) {
    float r; asm("v_exp_f32 %0, %1" : "=v"(r) : "v"(x)); return r;
}
__device__ __forceinline__ float flog2(float x) {
    float r; asm("v_log_f32 %0, %1" : "=v"(r) : "v"(x)); return r;
}

// ---------------------------------------------------------------------------
// K1 v5: pure register streaming, 2 priors/thread, ALL loads issued before
// ANY compute (distinct registers -> one waitcnt, ~14 loads in flight/thread).
// No LDS hist, no atomics, no memset dependency. Per-block partials only.
// ---------------------------------------------------------------------------
__global__ __launch_bounds__(K1_BLK) void k1_compute(
    const float* __restrict__ conf, const float* __restrict__ pred,
    const int* __restrict__ labels, const float* __restrict__ gt,
    unsigned* __restrict__ keys, float* __restrict__ pce,
    float* __restrict__ psl1, int* __restrict__ pcnt)
{
    __shared__ float wce[4], wsl[4];
    __shared__ int   wcnt[4];

    const int tid = threadIdx.x;
    const int lane = tid & 63;
    const int wid = tid >> 6;
    const size_t p0 = (size_t)blockIdx.x * TILE + tid;
    const size_t p1 = p0 + K1_BLK;

    // ---- issue ALL loads up front, nothing consumed yet
    const int lab0 = labels[p0];
    const int lab1 = labels[p1];
    const float* cp0 = conf + p0 * CC;
    const float* cp1 = conf + p1 * CC;
    f4 A0, A1, A2, A3, A4, B0, B1, B2, B3, B4;
    __builtin_memcpy(&A0, cp0 +  0, 16);
    __builtin_memcpy(&A1, cp0 +  4, 16);
    __builtin_memcpy(&A2, cp0 +  8, 16);
    __builtin_memcpy(&A3, cp0 + 12, 16);
    __builtin_memcpy(&A4, cp0 + 16, 16);
    __builtin_memcpy(&B0, cp1 +  0, 16);
    __builtin_memcpy(&B1, cp1 +  4, 16);
    __builtin_memcpy(&B2, cp1 +  8, 16);
    __builtin_memcpy(&B3, cp1 + 12, 16);
    __builtin_memcpy(&B4, cp1 + 16, 16);
    const float a20 = cp0[20];
    const float b20 = cp1[20];

    const bool pos0 = lab0 > 0;
    const bool pos1 = lab1 > 0;

    // sparse (~3%) SmoothL1 for both priors
    float sl = 0.f;
    if (pos0) {
        const float* pp = pred + p0 * 5;
        const float* gg = gt + p0 * 5;
#pragma unroll
        for (int j = 0; j < 5; ++j) {
            float d = fabsf(pp[j] - gg[j]);
            sl += (d < 1.f) ? 0.5f * d * d : (d - 0.5f);
        }
    }
    if (pos1) {
        const float* pp = pred + p1 * 5;
        const float* gg = gt + p1 * 5;
#pragma unroll
        for (int j = 0; j < 5; ++j) {
            float d = fabsf(pp[j] - gg[j]);
            sl += (d < 1.f) ? 0.5f * d * d : (d - 0.5f);
        }
    }

    // ---- prior 0: 21-class lse + logp[lab] gather via selects
    float s0 = 0.f, cl0 = 0.f;
#define KS(Q, J, IDX, LAB, SACC, CACC) { const float v_ = Q[J]; \
        SACC += fexp2(v_ * 1.44269504f); \
        CACC = ((IDX) == (LAB)) ? v_ : CACC; }
    KS(A0,0,0,lab0,s0,cl0) KS(A0,1,1,lab0,s0,cl0) KS(A0,2,2,lab0,s0,cl0) KS(A0,3,3,lab0,s0,cl0)
    KS(A1,0,4,lab0,s0,cl0) KS(A1,1,5,lab0,s0,cl0) KS(A1,2,6,lab0,s0,cl0) KS(A1,3,7,lab0,s0,cl0)
    KS(A2,0,8,lab0,s0,cl0) KS(A2,1,9,lab0,s0,cl0) KS(A2,2,10,lab0,s0,cl0) KS(A2,3,11,lab0,s0,cl0)
    KS(A3,0,12,lab0,s0,cl0) KS(A3,1,13,lab0,s0,cl0) KS(A3,2,14,lab0,s0,cl0) KS(A3,3,15,lab0,s0,cl0)
    KS(A4,0,16,lab0,s0,cl0) KS(A4,1,17,lab0,s0,cl0) KS(A4,2,18,lab0,s0,cl0) KS(A4,3,19,lab0,s0,cl0)
    { const float v_ = a20; s0 += fexp2(v_ * 1.44269504f); cl0 = (20 == lab0) ? v_ : cl0; }
    const float lse0 = 0.6931471805599453f * flog2(s0);
    const float mining0 = fmaxf(lse0 - A0[0], 0.f);
    keys[p0] = pos0 ? 0u : __float_as_uint(mining0);
    float ce = pos0 ? (lse0 - cl0) : 0.f;
    int cnt = pos0 ? 1 : 0;

    // ---- prior 1
    float s1 = 0.f, cl1 = 0.f;
    KS(B0,0,0,lab1,s1,cl1) KS(B0,1,1,lab1,s1,cl1) KS(B0,2,2,lab1,s1,cl1) KS(B0,3,3,lab1,s1,cl1)
    KS(B1,0,4,lab1,s1,cl1) KS(B1,1,5,lab1,s1,cl1) KS(B1,2,6,lab1,s1,cl1) KS(B1,3,7,lab1,s1,cl1)
    KS(B2,0,8,lab1,s1,cl1) KS(B2,1,9,lab1,s1,cl1) KS(B2,2,10,lab1,s1,cl1) KS(B2,3,11,lab1,s1,cl1)
    KS(B3,0,12,lab1,s1,cl1) KS(B3,1,13,lab1,s1,cl1) KS(B3,2,14,lab1,s1,cl1) KS(B3,3,15,lab1,s1,cl1)
    KS(B4,0,16,lab1,s1,cl1) KS(B4,1,17,lab1,s1,cl1) KS(B4,2,18,lab1,s1,cl1) KS(B4,3,19,lab1,s1,cl1)
    { const float v_ = b20; s1 += fexp2(v_ * 1.44269504f); cl1 = (20 == lab1) ? v_ : cl1; }
#undef KS
    const float lse1 = 0.6931471805599453f * flog2(s1);
    const float mining1 = fmaxf(lse1 - B0[0], 0.f);
    keys[p1] = pos1 ? 0u : __float_as_uint(mining1);
    ce += pos1 ? (lse1 - cl1) : 0.f;
    cnt += pos1 ? 1 : 0;

    // ---- deterministic block reduction (fixed trees)
#pragma unroll
    for (int d = 32; d > 0; d >>= 1) {
        ce  += __shfl_down(ce, d);
        sl  += __shfl_down(sl, d);
        cnt += __shfl_down(cnt, d);
    }
    if (lane == 0) { wce[wid] = ce; wsl[wid] = sl; wcnt[wid] = cnt; }
    __syncthreads();
    if (tid == 0) {
        float tce = 0.f, tsl = 0.f; int tc = 0;
#pragma unroll
        for (int w = 0; w < 4; ++w) { tce += wce[w]; tsl += wsl[w]; tc += wcnt[w]; }
        pce[blockIdx.x]  = tce;
        psl1[blockIdx.x] = tsl;
        pcnt[blockIdx.x] = tc;     // non-atomic per-block count
    }
}

// ---------------------------------------------------------------------------
// Suffix-scan over 2048 bins (2 bins/thread) + crossing pick (levels 2/3).
// ---------------------------------------------------------------------------
template <class GET>
__device__ __forceinline__ void sscan2048(
    GET get, unsigned* ss, unsigned* swsum,
    int* s_bin, int* s_above, unsigned want, int tid, int lane, int wid)
{
    const int b0 = 2047 - 2 * tid;     // descending scan order
    const int b1 = 2046 - 2 * tid;
    const unsigned m0 = get(b0), m1 = get(b1);
    unsigned v = m0 + m1;
#pragma unroll
    for (int d = 1; d < 64; d <<= 1) {
        unsigned u = __shfl_up(v, d);
        if (lane >= d) v += u;
    }
    if (lane == 63) swsum[wid] = v;
    __syncthreads();
    if (wid == 0) {
        unsigned wv = (lane < 16) ? swsum[lane] : 0;
#pragma unroll
        for (int d = 1; d < 16; d <<= 1) {
            unsigned u = __shfl_up(wv, d);
            if (lane >= d) wv += u;
        }
        if (lane < 16) swsum[lane] = wv;
    }
    __syncthreads();
    const unsigned off = wid ? swsum[wid - 1] : 0;
    const unsigned incl = off + v;     // suffix through b1
    const unsigned sb0 = incl - m1;    // suffix through b0
    ss[b0] = sb0;
    ss[b1] = incl;
    __syncthreads();
    if (sb0 >= want && (b0 == 2047 || ss[b0 + 1] < want)) {
        *s_bin = b0; *s_above = (b0 == 2047) ? 0 : (int)ss[b0 + 1];
    }
    if (incl >= want && ss[b1 + 1] < want) {
        *s_bin = b1; *s_above = (int)ss[b1 + 1];
    }
    __syncthreads();
}

// ---------------------------------------------------------------------------
// K2 v5: per-row exact top-k sum; builds its own level-1 hist (1024 bins:
// top-11 bits of any finite non-negative float <= 1020). Then gather pass +
// two LDS-resident refine levels. sum = Σ(key > T) + r·T (ties exact: a
// tied negative's CE equals T; zero-keys (positives) contribute exactly 0,
// matching the reference's mask-union semantics even when 3*npos > #neg).
// ---------------------------------------------------------------------------
__global__ __launch_bounds__(K2T) void k2_select(
    const unsigned* __restrict__ keys, const int* __restrict__ pcnt,
    double* __restrict__ row_sumneg)
{
    const int b = blockIdx.x;
    const int tid = threadIdx.x;
    const int lane = tid & 63;
    const int wid = tid >> 6;
    const unsigned* rk = keys + (size_t)b * NN;

    __shared__ unsigned lh[4096];     // 16 KB: L1 = 4-copy x 1024; L2/3 = 2-copy x 2048
    __shared__ unsigned ss[2048];     // 8 KB suffix sums
    __shared__ unsigned cbuf[CAP];    // 64 KB compacted keys
    __shared__ unsigned swsum[16];
    __shared__ double sdred[16];
    __shared__ int s_bin, s_above;
    __shared__ unsigned s_m, s_want;

    // want = min(3 * row positives, NN); reduce 64 per-block counts
    if (wid == 0) {
        int c = pcnt[b * BLKROW + lane];          // BLKROW == 64 == wave
#pragma unroll
        for (int d = 32; d > 0; d >>= 1) c += __shfl_down(c, d);
        if (lane == 0) s_want = (unsigned)((3 * c > NN) ? NN : 3 * c);
    }
    for (int i = tid; i < 4096; i += K2T) lh[i] = 0;
    __syncthreads();
    const unsigned want = s_want;
    if (want == 0) { if (tid == 0) row_sumneg[b] = 0.0; return; }

    // ---- pass 1: level-1 histogram (1024 bins, 4 interleaved copies)
    for (int i = tid; i < NN; i += K2T)
        atomicAdd(&lh[((rk[i] >> 21) << 2) | (lane & 3)], 1u);
    __syncthreads();

    // ---- level-1 scan: one bin per thread, descending
    {
        const int bn = 1023 - tid;
        const unsigned mv = lh[bn * 4] + lh[bn * 4 + 1] + lh[bn * 4 + 2] + lh[bn * 4 + 3];
        unsigned v = mv;
#pragma unroll
        for (int d = 1; d < 64; d <<= 1) {
            unsigned u = __shfl_up(v, d);
            if (lane >= d) v += u;
        }
        if (lane == 63) swsum[wid] = v;
        __syncthreads();
        if (wid == 0) {
            unsigned wv = (lane < 16) ? swsum[lane] : 0;
#pragma unroll
            for (int d = 1; d < 16; d <<= 1) {
                unsigned u = __shfl_up(wv, d);
                if (lane >= d) wv += u;
            }
            if (lane < 16) swsum[lane] = wv;
        }
        __syncthreads();
        const unsigned incl = (wid ? swsum[wid - 1] : 0) + v;
        ss[bn] = incl;
        __syncthreads();
        if (incl >= want && (bn == 1023 || ss[bn + 1] < want)) {
            s_bin = bn; s_above = (bn == 1023) ? 0 : (int)ss[bn + 1];
        }
        __syncthreads();
    }
    const int bsel1 = s_bin;
    unsigned want1 = want - (unsigned)s_above;
    const unsigned cnt1 = lh[bsel1 * 4] + lh[bsel1 * 4 + 1] +
                          lh[bsel1 * 4 + 2] + lh[bsel1 * 4 + 3];
    const bool fits = (cnt1 <= CAP);

    // ---- pass 2: gather matching keys + double-sum of keys above bin
    if (tid == 0) s_m = 0;
    __syncthreads();
    double localAbove = 0.0;
    for (int i = tid; i < NN; i += K2T) {
        const unsigned key = rk[i];
        const int hb = (int)(key >> 21);
        if (hb > bsel1) localAbove += (double)__uint_as_float(key);
        const bool take = fits && (hb == bsel1);
        const unsigned long long mask = __ballot(take);
        if (mask) {
            const int leader = __ffsll(mask) - 1;
            unsigned base = 0;
            if (lane == leader) base = atomicAdd(&s_m, (unsigned)__popcll(mask));
            base = __shfl(base, leader);
            if (take) {
                const unsigned pp = base +
                    (unsigned)__popcll(mask & ((1ull << lane) - 1ull));
                cbuf[pp] = key;   // pp < cnt1 <= CAP guaranteed
            }
        }
    }
    __syncthreads();
    const unsigned m = s_m;

    // ---- level 2: bits[20:10] (2048 bins, 2 copies)
    for (int i = tid; i < 4096; i += K2T) lh[i] = 0;
    __syncthreads();
    if (fits) {
        for (unsigned j = tid; j < m; j += K2T) {
            const unsigned key = cbuf[j];
            atomicAdd(&lh[(((key >> 10) & 0x7FFu) << 1) | (lane & 1)], 1u);
        }
    } else {
        for (int i = tid; i < NN; i += K2T) {
            const unsigned key = rk[i];
            if ((int)(key >> 21) == bsel1)
                atomicAdd(&lh[(((key >> 10) & 0x7FFu) << 1) | (lane & 1)], 1u);
        }
    }
    __syncthreads();
    sscan2048([&](int bn) { return lh[bn << 1] + lh[(bn << 1) | 1]; },
              ss, swsum, &s_bin, &s_above, want1, tid, lane, wid);
    const unsigned bsel2 = (unsigned)s_bin;
    unsigned want2 = want1 - (unsigned)s_above;

    // ---- level 3: bits[9:0] (1024 live bins; upper 1024 stay zero)
    for (int i = tid; i < 4096; i += K2T) lh[i] = 0;
    __syncthreads();
    if (fits) {
        for (unsigned j = tid; j < m; j += K2T) {
            const unsigned key = cbuf[j];
            if (((key >> 10) & 0x7FFu) == bsel2)
                atomicAdd(&lh[((key & 0x3FFu) << 1) | (lane & 1)], 1u);
        }
    } else {
        for (int i = tid; i < NN; i += K2T) {
            const unsigned key = rk[i];
            if ((int)(key >> 21) == bsel1 && ((key >> 10) & 0x7FFu) == bsel2)
                atomicAdd(&lh[((key & 0x3FFu) << 1) | (lane & 1)], 1u);
        }
    }
    __syncthreads();
    sscan2048([&](int bn) { return lh[bn << 1] + lh[(bn << 1) | 1]; },
              ss, swsum, &s_bin, &s_above, want2, tid, lane, wid);
    const int r = (int)want2 - s_above;           // # of ==T selected
    const unsigned T = ((unsigned)bsel1 << 21) | (bsel2 << 10) | (unsigned)s_bin;

    // ---- final: sum of in-bin keys strictly greater than T
    double localSel = 0.0;
    if (fits) {
        for (unsigned j = tid; j < m; j += K2T) {
            const unsigned key = cbuf[j];
            if (key > T) localSel += (double)__uint_as_float(key);
        }
    } else {
        for (int i = tid; i < NN; i += K2T) {
            const unsigned key = rk[i];
            if ((int)(key >> 21) == bsel1 && key > T)
                localSel += (double)__uint_as_float(key);
        }
    }
    double tot = localAbove + localSel;
#pragma unroll
    for (int d = 32; d > 0; d >>= 1) tot += __shfl_down(tot, d);
    if (lane == 0) sdred[wid] = tot;
    __syncthreads();
    if (tid == 0) {
        double sm = 0.0;
#pragma unroll
        for (int w = 0; w < 16; ++w) sm += sdred[w];
        row_sumneg[b] = sm + (double)r * (double)__uint_as_float(T);
    }
}

// ---------------------------------------------------------------------------
// K3: deterministic final reduction -> two scalars.
// ---------------------------------------------------------------------------
__global__ __launch_bounds__(256) void k3_final(
    const float* __restrict__ pce, const float* __restrict__ psl1,
    const int* __restrict__ pcnt, const double* __restrict__ row_sumneg,
    float* __restrict__ out)
{
    __shared__ double a[256], c[256];
    __shared__ int ic[256];
    const int tid = threadIdx.x;
    double ce = 0.0, sl = 0.0; int np = 0;
    for (int i = tid; i < K1_GRID; i += 256) {
        ce += (double)pce[i];
        sl += (double)psl1[i];
        np += pcnt[i];
    }
    a[tid] = ce; c[tid] = sl; ic[tid] = np;
    __syncthreads();
    for (int st = 128; st > 0; st >>= 1) {
        if (tid < st) {
            a[tid] += a[tid + st];
            c[tid] += c[tid + st];
            ic[tid] += ic[tid + st];
        }
        __syncthreads();
    }
    if (tid == 0) {
        double ns = 0.0;
        for (int bb = 0; bb < BB; ++bb) ns += row_sumneg[bb];
        const double npos = (double)ic[0];
        out[0] = (float)(c[0] / npos);          // smooth_l1_loss / n_pos
        out[1] = (float)((a[0] + ns) / npos);   // classification_loss / n_pos
    }
}

// ---------------------------------------------------------------------------
extern "C" void kernel_launch(void* const* d_in, const int* in_sizes, int n_in,
                              void* d_out, int out_size, void* d_ws, size_t ws_size,
                              hipStream_t stream)
{
    const float* conf   = (const float*)d_in[0];
    const float* pred   = (const float*)d_in[1];
    const int*   labels = (const int*)d_in[2];
    const float* gt     = (const float*)d_in[3];
    float* out = (float*)d_out;

    char* ws = (char*)d_ws;
    unsigned* keys       = (unsigned*)ws;                      // 4 MB
    float*    pce        = (float*)(ws + 4194304);             // 8 KB
    float*    psl1       = (float*)(ws + 4202496);             // 8 KB
    int*      pcnt       = (int*)(ws + 4210688);               // 8 KB
    double*   row_sumneg = (double*)(ws + 4218880);            // 256 B

    k1_compute<<<K1_GRID, K1_BLK, 0, stream>>>(conf, pred, labels, gt,
                                               keys, pce, psl1, pcnt);
    k2_select<<<BB, K2T, 0, stream>>>(keys, pcnt, row_sumneg);
    k3_final<<<1, 256, 0, stream>>>(pce, psl1, pcnt, row_sumneg, out);
}

// Round 6
// 39.522 us; speedup vs baseline: 2.5110x; 1.3554x over previous
//
#include <hip/hip_runtime.h>
#include <cstdint>

// Problem constants (match reference)
#define BB 32
#define NN 32768
#define CC 21
#define K1_BLK 256
#define PPT 2                                  // priors per thread
#define TILE (K1_BLK * PPT)                    // 512
#define K1_GRID ((BB * NN) / TILE)             // 2048
#define BLKROW (NN / TILE)                     // 64 k1-blocks per row

// K2 geometry
#define K2T 1024
#define KPT (NN / K2T)                         // 32 keys per thread
#define NC 16                                  // level-1 hist copies

typedef float f4 __attribute__((ext_vector_type(4)));

// native transcendentals (1-ulp; output threshold 0.39 absolute -> huge slack)
__device__ __forceinline__ float fexp2(float x) {
    float r; asm("v_exp_f32 %0, %1" : "=v"(r) : "v"(x)); return r;
}
__device__ __forceinline__ float flog2(float x) {
    float r; asm("v_log_f32 %0, %1" : "=v"(r) : "v"(x)); return r;
}

// ---------------------------------------------------------------------------
// K1 v5 (unchanged): register streaming, 2 priors/thread, all loads batched.
// ---------------------------------------------------------------------------
__global__ __launch_bounds__(K1_BLK) void k1_compute(
    const float* __restrict__ conf, const float* __restrict__ pred,
    const int* __restrict__ labels, const float* __restrict__ gt,
    unsigned* __restrict__ keys, float* __restrict__ pce,
    float* __restrict__ psl1, int* __restrict__ pcnt)
{
    __shared__ float wce[4], wsl[4];
    __shared__ int   wcnt[4];

    const int tid = threadIdx.x;
    const int lane = tid & 63;
    const int wid = tid >> 6;
    const size_t p0 = (size_t)blockIdx.x * TILE + tid;
    const size_t p1 = p0 + K1_BLK;

    // ---- issue ALL loads up front, nothing consumed yet
    const int lab0 = labels[p0];
    const int lab1 = labels[p1];
    const float* cp0 = conf + p0 * CC;
    const float* cp1 = conf + p1 * CC;
    f4 A0, A1, A2, A3, A4, B0, B1, B2, B3, B4;
    __builtin_memcpy(&A0, cp0 +  0, 16);
    __builtin_memcpy(&A1, cp0 +  4, 16);
    __builtin_memcpy(&A2, cp0 +  8, 16);
    __builtin_memcpy(&A3, cp0 + 12, 16);
    __builtin_memcpy(&A4, cp0 + 16, 16);
    __builtin_memcpy(&B0, cp1 +  0, 16);
    __builtin_memcpy(&B1, cp1 +  4, 16);
    __builtin_memcpy(&B2, cp1 +  8, 16);
    __builtin_memcpy(&B3, cp1 + 12, 16);
    __builtin_memcpy(&B4, cp1 + 16, 16);
    const float a20 = cp0[20];
    const float b20 = cp1[20];

    const bool pos0 = lab0 > 0;
    const bool pos1 = lab1 > 0;

    // sparse (~3%) SmoothL1 for both priors
    float sl = 0.f;
    if (pos0) {
        const float* pp = pred + p0 * 5;
        const float* gg = gt + p0 * 5;
#pragma unroll
        for (int j = 0; j < 5; ++j) {
            float d = fabsf(pp[j] - gg[j]);
            sl += (d < 1.f) ? 0.5f * d * d : (d - 0.5f);
        }
    }
    if (pos1) {
        const float* pp = pred + p1 * 5;
        const float* gg = gt + p1 * 5;
#pragma unroll
        for (int j = 0; j < 5; ++j) {
            float d = fabsf(pp[j] - gg[j]);
            sl += (d < 1.f) ? 0.5f * d * d : (d - 0.5f);
        }
    }

    // ---- prior 0: 21-class lse + logp[lab] gather via selects
    float s0 = 0.f, cl0 = 0.f;
#define KS(Q, J, IDX, LAB, SACC, CACC) { const float v_ = Q[J]; \
        SACC += fexp2(v_ * 1.44269504f); \
        CACC = ((IDX) == (LAB)) ? v_ : CACC; }
    KS(A0,0,0,lab0,s0,cl0) KS(A0,1,1,lab0,s0,cl0) KS(A0,2,2,lab0,s0,cl0) KS(A0,3,3,lab0,s0,cl0)
    KS(A1,0,4,lab0,s0,cl0) KS(A1,1,5,lab0,s0,cl0) KS(A1,2,6,lab0,s0,cl0) KS(A1,3,7,lab0,s0,cl0)
    KS(A2,0,8,lab0,s0,cl0) KS(A2,1,9,lab0,s0,cl0) KS(A2,2,10,lab0,s0,cl0) KS(A2,3,11,lab0,s0,cl0)
    KS(A3,0,12,lab0,s0,cl0) KS(A3,1,13,lab0,s0,cl0) KS(A3,2,14,lab0,s0,cl0) KS(A3,3,15,lab0,s0,cl0)
    KS(A4,0,16,lab0,s0,cl0) KS(A4,1,17,lab0,s0,cl0) KS(A4,2,18,lab0,s0,cl0) KS(A4,3,19,lab0,s0,cl0)
    { const float v_ = a20; s0 += fexp2(v_ * 1.44269504f); cl0 = (20 == lab0) ? v_ : cl0; }
    const float lse0 = 0.6931471805599453f * flog2(s0);
    const float mining0 = fmaxf(lse0 - A0[0], 0.f);
    keys[p0] = pos0 ? 0u : __float_as_uint(mining0);
    float ce = pos0 ? (lse0 - cl0) : 0.f;
    int cnt = pos0 ? 1 : 0;

    // ---- prior 1
    float s1 = 0.f, cl1 = 0.f;
    KS(B0,0,0,lab1,s1,cl1) KS(B0,1,1,lab1,s1,cl1) KS(B0,2,2,lab1,s1,cl1) KS(B0,3,3,lab1,s1,cl1)
    KS(B1,0,4,lab1,s1,cl1) KS(B1,1,5,lab1,s1,cl1) KS(B1,2,6,lab1,s1,cl1) KS(B1,3,7,lab1,s1,cl1)
    KS(B2,0,8,lab1,s1,cl1) KS(B2,1,9,lab1,s1,cl1) KS(B2,2,10,lab1,s1,cl1) KS(B2,3,11,lab1,s1,cl1)
    KS(B3,0,12,lab1,s1,cl1) KS(B3,1,13,lab1,s1,cl1) KS(B3,2,14,lab1,s1,cl1) KS(B3,3,15,lab1,s1,cl1)
    KS(B4,0,16,lab1,s1,cl1) KS(B4,1,17,lab1,s1,cl1) KS(B4,2,18,lab1,s1,cl1) KS(B4,3,19,lab1,s1,cl1)
    { const float v_ = b20; s1 += fexp2(v_ * 1.44269504f); cl1 = (20 == lab1) ? v_ : cl1; }
#undef KS
    const float lse1 = 0.6931471805599453f * flog2(s1);
    const float mining1 = fmaxf(lse1 - B0[0], 0.f);
    keys[p1] = pos1 ? 0u : __float_as_uint(mining1);
    ce += pos1 ? (lse1 - cl1) : 0.f;
    cnt += pos1 ? 1 : 0;

    // ---- deterministic block reduction (fixed trees)
#pragma unroll
    for (int d = 32; d > 0; d >>= 1) {
        ce  += __shfl_down(ce, d);
        sl  += __shfl_down(sl, d);
        cnt += __shfl_down(cnt, d);
    }
    if (lane == 0) { wce[wid] = ce; wsl[wid] = sl; wcnt[wid] = cnt; }
    __syncthreads();
    if (tid == 0) {
        float tce = 0.f, tsl = 0.f; int tc = 0;
#pragma unroll
        for (int w = 0; w < 4; ++w) { tce += wce[w]; tsl += wsl[w]; tc += wcnt[w]; }
        pce[blockIdx.x]  = tce;
        psl1[blockIdx.x] = tsl;
        pcnt[blockIdx.x] = tc;     // non-atomic per-block count
    }
}

// ---------------------------------------------------------------------------
// Suffix-scan over 2048 bins (2 bins/thread) + crossing pick.
// ---------------------------------------------------------------------------
template <class GET>
__device__ __forceinline__ void sscan2048(
    GET get, unsigned* ss, unsigned* swsum,
    int* s_bin, int* s_above, unsigned want, int tid, int lane, int wid)
{
    const int b0 = 2047 - 2 * tid;     // descending scan order
    const int b1 = 2046 - 2 * tid;
    const unsigned m0 = get(b0), m1 = get(b1);
    unsigned v = m0 + m1;
#pragma unroll
    for (int d = 1; d < 64; d <<= 1) {
        unsigned u = __shfl_up(v, d);
        if (lane >= d) v += u;
    }
    if (lane == 63) swsum[wid] = v;
    __syncthreads();
    if (wid == 0) {
        unsigned wv = (lane < 16) ? swsum[lane] : 0;
#pragma unroll
        for (int d = 1; d < 16; d <<= 1) {
            unsigned u = __shfl_up(wv, d);
            if (lane >= d) wv += u;
        }
        if (lane < 16) swsum[lane] = wv;
    }
    __syncthreads();
    const unsigned off = wid ? swsum[wid - 1] : 0;
    const unsigned incl = off + v;     // suffix through b1
    const unsigned sb0 = incl - m1;    // suffix through b0
    ss[b0] = sb0;
    ss[b1] = incl;
    __syncthreads();
    if (sb0 >= want && (b0 == 2047 || ss[b0 + 1] < want)) {
        *s_bin = b0; *s_above = (b0 == 2047) ? 0 : (int)ss[b0 + 1];
    }
    if (incl >= want && ss[b1 + 1] < want) {
        *s_bin = b1; *s_above = (int)ss[b1 + 1];
    }
    __syncthreads();
}

// ---------------------------------------------------------------------------
// K2 v6: fully register-resident. One coalesced global read of the row
// (32 keys/thread in VGPRs). Level 1: 1024-bin hist, 16 interleaved copies
// (hot-bin atomic serialization /16). Levels 2/3: predicated hist straight
// from registers. Final: one register pass, sum = Σ(key>T) + r·T (exact:
// a tied negative's CE equals T; positive keys are 0 and contribute 0).
// ---------------------------------------------------------------------------
__global__ __launch_bounds__(K2T) void k2_select(
    const unsigned* __restrict__ keys, const int* __restrict__ pcnt,
    double* __restrict__ row_sumneg)
{
    const int b = blockIdx.x;
    const int tid = threadIdx.x;
    const int lane = tid & 63;
    const int wid = tid >> 6;
    const unsigned* rk = keys + (size_t)b * NN;

    __shared__ unsigned h1[1024 * NC];  // 64 KB (reused for levels 2/3)
    __shared__ unsigned ss[2048];       // 8 KB suffix sums
    __shared__ unsigned swsum[16];
    __shared__ double sdred[16];
    __shared__ int s_bin, s_above;
    __shared__ unsigned s_want;

    // ---- one coalesced read: 8 x uint4 per thread -> 32 keys in VGPRs
    uint4 kv[8];
    const uint4* rk4 = reinterpret_cast<const uint4*>(rk);
#pragma unroll
    for (int j = 0; j < 8; ++j) kv[j] = rk4[tid + j * K2T];

    // want = min(3 * row positives, NN)
    if (wid == 0) {
        int c = pcnt[b * BLKROW + lane];          // BLKROW == 64 == wave
#pragma unroll
        for (int d = 32; d > 0; d >>= 1) c += __shfl_down(c, d);
        if (lane == 0) s_want = (unsigned)((3 * c > NN) ? NN : 3 * c);
    }
    for (int i = tid; i < 1024 * NC; i += K2T) h1[i] = 0;
    __syncthreads();
    const unsigned want = s_want;
    if (want == 0) { if (tid == 0) row_sumneg[b] = 0.0; return; }

    // ---- level 1: 1024-bin hist of bits[31:21] (finite >=0 -> bin <= 1019)
    const unsigned cp = lane & (NC - 1);
#pragma unroll
    for (int j = 0; j < 8; ++j) {
        atomicAdd(&h1[((kv[j].x >> 21) << 4) | cp], 1u);
        atomicAdd(&h1[((kv[j].y >> 21) << 4) | cp], 1u);
        atomicAdd(&h1[((kv[j].z >> 21) << 4) | cp], 1u);
        atomicAdd(&h1[((kv[j].w >> 21) << 4) | cp], 1u);
    }
    __syncthreads();

    // ---- level-1 scan: one bin/thread, descending suffix sums
    {
        const int bn = 1023 - tid;
        unsigned mv = 0;
#pragma unroll
        for (int c = 0; c < NC; ++c) mv += h1[(bn << 4) | c];
        unsigned v = mv;
#pragma unroll
        for (int d = 1; d < 64; d <<= 1) {
            unsigned u = __shfl_up(v, d);
            if (lane >= d) v += u;
        }
        if (lane == 63) swsum[wid] = v;
        __syncthreads();
        if (wid == 0) {
            unsigned wv = (lane < 16) ? swsum[lane] : 0;
#pragma unroll
            for (int d = 1; d < 16; d <<= 1) {
                unsigned u = __shfl_up(wv, d);
                if (lane >= d) wv += u;
            }
            if (lane < 16) swsum[lane] = wv;
        }
        __syncthreads();
        const unsigned incl = (wid ? swsum[wid - 1] : 0) + v;
        ss[bn] = incl;
        __syncthreads();
        if (incl >= want && (bn == 1023 || ss[bn + 1] < want)) {
            s_bin = bn; s_above = (bn == 1023) ? 0 : (int)ss[bn + 1];
        }
        __syncthreads();
    }
    const unsigned bsel1 = (unsigned)s_bin;
    const unsigned want1 = want - (unsigned)s_above;

    // ---- level 2: bits[20:10] of in-bin keys, straight from registers
    for (int i = tid; i < 4096; i += K2T) h1[i] = 0;
    __syncthreads();
    const unsigned c2 = lane & 1;
#pragma unroll
    for (int j = 0; j < 8; ++j) {
#define L2ADD(K) if (((K) >> 21) == bsel1) \
        atomicAdd(&h1[((((K) >> 10) & 0x7FFu) << 1) | c2], 1u);
        L2ADD(kv[j].x) L2ADD(kv[j].y) L2ADD(kv[j].z) L2ADD(kv[j].w)
#undef L2ADD
    }
    __syncthreads();
    sscan2048([&](int bn) { return h1[bn << 1] + h1[(bn << 1) | 1]; },
              ss, swsum, &s_bin, &s_above, want1, tid, lane, wid);
    const unsigned bsel2 = (unsigned)s_bin;
    const unsigned want2 = want1 - (unsigned)s_above;

    // ---- level 3: bits[9:0] (1024 live bins; upper 1024 stay zero)
    for (int i = tid; i < 4096; i += K2T) h1[i] = 0;
    __syncthreads();
    const unsigned pref = (bsel1 << 11) | bsel2;   // bits[31:10] match value
#pragma unroll
    for (int j = 0; j < 8; ++j) {
#define L3ADD(K) if (((K) >> 10) == pref) \
        atomicAdd(&h1[(((K) & 0x3FFu) << 1) | c2], 1u);
        L3ADD(kv[j].x) L3ADD(kv[j].y) L3ADD(kv[j].z) L3ADD(kv[j].w)
#undef L3ADD
    }
    __syncthreads();
    sscan2048([&](int bn) { return h1[bn << 1] + h1[(bn << 1) | 1]; },
              ss, swsum, &s_bin, &s_above, want2, tid, lane, wid);
    const unsigned T = (bsel1 << 21) | (bsel2 << 10) | (unsigned)s_bin;

    // ---- final: one register pass over all 32 keys
    int above = 0;
    double sel = 0.0;
#pragma unroll
    for (int j = 0; j < 8; ++j) {
#define FIN(K) if ((K) > T) { above++; sel += (double)__uint_as_float(K); }
        FIN(kv[j].x) FIN(kv[j].y) FIN(kv[j].z) FIN(kv[j].w)
#undef FIN
    }
#pragma unroll
    for (int d = 32; d > 0; d >>= 1) {
        above += __shfl_down(above, d);
        sel   += __shfl_down(sel, d);
    }
    if (lane == 0) { swsum[wid] = (unsigned)above; sdred[wid] = sel; }
    __syncthreads();
    if (tid == 0) {
        unsigned atot = 0; double stot = 0.0;
#pragma unroll
        for (int w = 0; w < 16; ++w) { atot += swsum[w]; stot += sdred[w]; }
        const int r = (int)want - (int)atot;   // # of ==T entries selected
        row_sumneg[b] = stot + (double)r * (double)__uint_as_float(T);
    }
}

// ---------------------------------------------------------------------------
// K3: deterministic final reduction -> two scalars.
// ---------------------------------------------------------------------------
__global__ __launch_bounds__(256) void k3_final(
    const float* __restrict__ pce, const float* __restrict__ psl1,
    const int* __restrict__ pcnt, const double* __restrict__ row_sumneg,
    float* __restrict__ out)
{
    __shared__ double a[256], c[256];
    __shared__ int ic[256];
    const int tid = threadIdx.x;
    double ce = 0.0, sl = 0.0; int np = 0;
    for (int i = tid; i < K1_GRID; i += 256) {
        ce += (double)pce[i];
        sl += (double)psl1[i];
        np += pcnt[i];
    }
    a[tid] = ce; c[tid] = sl; ic[tid] = np;
    __syncthreads();
    for (int st = 128; st > 0; st >>= 1) {
        if (tid < st) {
            a[tid] += a[tid + st];
            c[tid] += c[tid + st];
            ic[tid] += ic[tid + st];
        }
        __syncthreads();
    }
    if (tid == 0) {
        double ns = 0.0;
        for (int bb = 0; bb < BB; ++bb) ns += row_sumneg[bb];
        const double npos = (double)ic[0];
        out[0] = (float)(c[0] / npos);          // smooth_l1_loss / n_pos
        out[1] = (float)((a[0] + ns) / npos);   // classification_loss / n_pos
    }
}

// ---------------------------------------------------------------------------
extern "C" void kernel_launch(void* const* d_in, const int* in_sizes, int n_in,
                              void* d_out, int out_size, void* d_ws, size_t ws_size,
                              hipStream_t stream)
{
    const float* conf   = (const float*)d_in[0];
    const float* pred   = (const float*)d_in[1];
    const int*   labels = (const int*)d_in[2];
    const float* gt     = (const float*)d_in[3];
    float* out = (float*)d_out;

    char* ws = (char*)d_ws;
    unsigned* keys       = (unsigned*)ws;                      // 4 MB
    float*    pce        = (float*)(ws + 4194304);             // 8 KB
    float*    psl1       = (float*)(ws + 4202496);             // 8 KB
    int*      pcnt       = (int*)(ws + 4210688);               // 8 KB
    double*   row_sumneg = (double*)(ws + 4218880);            // 256 B

    k1_compute<<<K1_GRID, K1_BLK, 0, stream>>>(conf, pred, labels, gt,
                                               keys, pce, psl1, pcnt);
    k2_select<<<BB, K2T, 0, stream>>>(keys, pcnt, row_sumneg);
    k3_final<<<1, 256, 0, stream>>>(pce, psl1, pcnt, row_sumneg, out);
}